// Round 3
// baseline (262.285 us; speedup 1.0000x reference)
//
#include <hip/hip_runtime.h>
#include <hip/hip_bf16.h>

// MLPDecoder: scores[e] = relu((h[src]*h[dst]) @ W1 + b1) @ W2 + b2
// E=300000, D=256. bf16 MFMA, 3-stage software pipeline, 1 barrier/iter.

#define E_EDGES 300000
#define DIM 256
#define MT 32                    // edges per block-iteration
#define NTILES (E_EDGES / MT)    // 9375
#define BLK 512                  // 8 waves; each wave owns 32 N-cols
#define GRID_MAIN 512            // 2 blocks/CU
#define MAXJ 19                  // ceil(9375/512)

typedef short bf16x8 __attribute__((ext_vector_type(8)));
typedef float f32x4 __attribute__((ext_vector_type(4)));

__device__ __forceinline__ ushort f2bf(float f) {
    union { float f; unsigned u; } v; v.f = f;
    unsigned r = v.u + 0x7FFFu + ((v.u >> 16) & 1u);  // RNE
    return (ushort)(r >> 16);
}

// W1 fp32 [K=256][N=256] -> W1^T bf16 [N][K]
__global__ void prep_w1t(const float* __restrict__ w1, ushort* __restrict__ w1t) {
    int idx = blockIdx.x * 256 + threadIdx.x;
    int k = idx >> 8, n = idx & 255;
    w1t[n * 256 + k] = f2bf(w1[k * 256 + n]);
}

// h fp32 -> bf16
__global__ void prep_hbf(const float* __restrict__ h, ushort* __restrict__ hbf) {
    int i = blockIdx.x * 256 + threadIdx.x;
    const float4* src = (const float4*)h + (size_t)i * 2;
    float4 a = src[0], b = src[1];
    union { ushort s[8]; uint4 v; } o;
    o.s[0] = f2bf(a.x); o.s[1] = f2bf(a.y); o.s[2] = f2bf(a.z); o.s[3] = f2bf(a.w);
    o.s[4] = f2bf(b.x); o.s[5] = f2bf(b.y); o.s[6] = f2bf(b.z); o.s[7] = f2bf(b.w);
    ((uint4*)hbf)[i] = o.v;
}

__global__ __launch_bounds__(BLK, 4)
void decoder(const ushort* __restrict__ hbf, const int2* __restrict__ edges,
             const ushort* __restrict__ w1t, const float* __restrict__ b1,
             const float* __restrict__ w2, const float* __restrict__ b2p,
             float* __restrict__ out) {
    // stride 264: uniform bank spread for b128 ops; double-buffered
    __shared__ ushort xlds[2][MT][264];   // 33.8 KB
    __shared__ float part[2][8][MT];      // 2 KB, double-buffered partials
    __shared__ int2 eld[MAXJ * MT];       // all this block's edge pairs (4.9 KB)

    const int t = threadIdx.x;
    const int w = t >> 6, lane = t & 63, quad = lane >> 4, l15 = lane & 15;
    const int bx = blockIdx.x, gd = gridDim.x;
    const int J = (NTILES - bx + gd - 1) / gd;   // tiles for this block (18 or 19)

    // ---- register-resident W1 frags: wave w owns N cols [32w, 32w+32) ----
    bf16x8 Bf[2][8];   // 64 VGPRs
#pragma unroll
    for (int nt = 0; nt < 2; ++nt) {
        int n = w * 32 + nt * 16 + l15;
#pragma unroll
        for (int ks = 0; ks < 8; ++ks)
            Bf[nt][ks] = *(const bf16x8*)(w1t + n * 256 + ks * 32 + quad * 8);
    }
    float b1v[2], w2v[2];
#pragma unroll
    for (int nt = 0; nt < 2; ++nt) {
        int n = w * 32 + nt * 16 + l15;
        b1v[nt] = b1[n];
        w2v[nt] = w2[n];
    }
    const float b2v = b2p[0];

    // ---- preload ALL this block's edge pairs into LDS ----
    for (int idx = t; idx < J * MT; idx += BLK) {
        int j = idx >> 5, i = idx & 31;
        eld[idx] = edges[(size_t)(bx + j * gd) * MT + i];
    }
    __syncthreads();

    const int sm = t >> 4;     // edge row in tile 0..31
    const int sc = t & 15;     // 32B chunk in row

    uint4 gs[2][2], gd4[2][2];  // prefetch regs, [tile&1][chunk]

    auto issue = [&](int j, int par) {     // par == j&1
        int2 ed = eld[j * MT + sm];
        const uint4* ps = (const uint4*)(hbf + (size_t)ed.x * DIM) + sc * 2;
        const uint4* pd = (const uint4*)(hbf + (size_t)ed.y * DIM) + sc * 2;
        gs[par][0] = ps[0]; gs[par][1] = ps[1];
        gd4[par][0] = pd[0]; gd4[par][1] = pd[1];
    };
    auto hadamard = [&](int par) {         // consumes buf par, writes xlds[par]
        const __hip_bfloat162* s2 = (const __hip_bfloat162*)gs[par];
        const __hip_bfloat162* d2 = (const __hip_bfloat162*)gd4[par];
        union { __hip_bfloat162 h2[8]; uint4 v[2]; } o;
#pragma unroll
        for (int q = 0; q < 8; ++q) o.h2[q] = __hmul2(s2[q], d2[q]);
        uint4* dst = (uint4*)&xlds[par][sm][sc * 16];
        dst[0] = o.v[0]; dst[1] = o.v[1];
    };

    // prologue: fill pipeline
    issue(0, 0);
    if (J > 1) issue(1, 1);
    hadamard(0);

    auto body = [&](int j, int par) {      // par == j&1
        __syncthreads();
        // finalize tile j-1 (partials written before the sync)
        if (j > 0 && t < MT) {
            float s = b2v;
#pragma unroll
            for (int ww = 0; ww < 8; ++ww) s += part[par ^ 1][ww][t];
            out[(size_t)(bx + (j - 1) * gd) * MT + t] = s;
        }
        // issue gathers 2 ahead (buf (j+2)&1 == par)
        if (j + 2 < J) issue(j + 2, par);
        // stage tile j+1 (buf and xlds index (j+1)&1 == par^1)
        if (j + 1 < J) hadamard(par ^ 1);

        // ---- MFMA on tile j from xlds[par] ----
        f32x4 acc[2][2];
#pragma unroll
        for (int ms = 0; ms < 2; ++ms)
#pragma unroll
            for (int nt = 0; nt < 2; ++nt)
                acc[ms][nt] = (f32x4){0.f, 0.f, 0.f, 0.f};
#pragma unroll
        for (int ks = 0; ks < 8; ++ks) {
            int kb = ks * 32 + quad * 8;
            bf16x8 a0 = *(const bf16x8*)&xlds[par][l15][kb];
            bf16x8 a1 = *(const bf16x8*)&xlds[par][16 + l15][kb];
#pragma unroll
            for (int nt = 0; nt < 2; ++nt) {
                acc[0][nt] = __builtin_amdgcn_mfma_f32_16x16x32_bf16(a0, Bf[nt][ks], acc[0][nt], 0, 0, 0);
                acc[1][nt] = __builtin_amdgcn_mfma_f32_16x16x32_bf16(a1, Bf[nt][ks], acc[1][nt], 0, 0, 0);
            }
        }
        // epilogue: relu(hid+b1).w2, butterfly over 16 n-lanes
        // C/D: row m = ms*16 + quad*4 + r, col n = w*32 + nt*16 + l15
        float red[2][4];
#pragma unroll
        for (int ms = 0; ms < 2; ++ms)
#pragma unroll
            for (int r = 0; r < 4; ++r) {
                float s = 0.f;
#pragma unroll
                for (int nt = 0; nt < 2; ++nt)
                    s += fmaxf(acc[ms][nt][r] + b1v[nt], 0.f) * w2v[nt];
                red[ms][r] = s;
            }
#pragma unroll
        for (int mask = 1; mask <= 8; mask <<= 1)
#pragma unroll
            for (int ms = 0; ms < 2; ++ms)
#pragma unroll
                for (int r = 0; r < 4; ++r)
                    red[ms][r] += __shfl_xor(red[ms][r], mask);
        if (l15 == 0)
#pragma unroll
            for (int ms = 0; ms < 2; ++ms)
#pragma unroll
                for (int r = 0; r < 4; ++r)
                    part[par][w][ms * 16 + quad * 4 + r] = red[ms][r];
    };

    // manual 2x unroll keeps buffer parity compile-time (no reg-array scatter)
    int j = 0;
    for (; j + 1 < J; j += 2) { body(j, 0); body(j + 1, 1); }
    if (j < J) body(j, j & 1);

    // drain: finalize last tile
    __syncthreads();
    if (t < MT) {
        float s = b2v;
#pragma unroll
        for (int ww = 0; ww < 8; ++ww) s += part[(J - 1) & 1][ww][t];
        out[(size_t)(bx + (J - 1) * gd) * MT + t] = s;
    }
}

// fp32-gather fallback (only if ws too small for hbf; not expected to run)
__global__ __launch_bounds__(BLK, 4)
void decoder_f32(const float* __restrict__ h, const int2* __restrict__ edges,
                 const ushort* __restrict__ w1t, const float* __restrict__ b1,
                 const float* __restrict__ w2, const float* __restrict__ b2p,
                 float* __restrict__ out) {
    __shared__ ushort xlds[MT][264];
    __shared__ float part[8][MT];
    const int t = threadIdx.x;
    const int w = t >> 6, lane = t & 63, quad = lane >> 4, l15 = lane & 15;
    bf16x8 Bf[2][8];
#pragma unroll
    for (int nt = 0; nt < 2; ++nt)
#pragma unroll
        for (int ks = 0; ks < 8; ++ks)
            Bf[nt][ks] = *(const bf16x8*)(w1t + (w * 32 + nt * 16 + l15) * 256 + ks * 32 + quad * 8);
    float b1v[2], w2v[2];
#pragma unroll
    for (int nt = 0; nt < 2; ++nt) {
        b1v[nt] = b1[w * 32 + nt * 16 + l15];
        w2v[nt] = w2[w * 32 + nt * 16 + l15];
    }
    const float b2v = b2p[0];
    const int sm = t >> 4, sc = t & 15;
    for (int mb = blockIdx.x; mb < NTILES; mb += gridDim.x) {
        int2 ed = edges[mb * MT + sm];
        const float4* ps = (const float4*)(h + (size_t)ed.x * DIM) + sc * 4;
        const float4* pd = (const float4*)(h + (size_t)ed.y * DIM) + sc * 4;
        union { ushort s[16]; uint4 v[2]; } o;
#pragma unroll
        for (int jj = 0; jj < 4; ++jj) {
            float4 a = ps[jj], b = pd[jj];
            o.s[4 * jj + 0] = f2bf(a.x * b.x); o.s[4 * jj + 1] = f2bf(a.y * b.y);
            o.s[4 * jj + 2] = f2bf(a.z * b.z); o.s[4 * jj + 3] = f2bf(a.w * b.w);
        }
        uint4* dst = (uint4*)&xlds[sm][sc * 16];
        dst[0] = o.v[0]; dst[1] = o.v[1];
        __syncthreads();
        f32x4 acc[2][2];
#pragma unroll
        for (int ms = 0; ms < 2; ++ms)
#pragma unroll
            for (int nt = 0; nt < 2; ++nt) acc[ms][nt] = (f32x4){0.f,0.f,0.f,0.f};
#pragma unroll
        for (int ks = 0; ks < 8; ++ks) {
            int kb = ks * 32 + quad * 8;
            bf16x8 a0 = *(const bf16x8*)&xlds[l15][kb];
            bf16x8 a1 = *(const bf16x8*)&xlds[16 + l15][kb];
#pragma unroll
            for (int nt = 0; nt < 2; ++nt) {
                acc[0][nt] = __builtin_amdgcn_mfma_f32_16x16x32_bf16(a0, Bf[nt][ks], acc[0][nt], 0, 0, 0);
                acc[1][nt] = __builtin_amdgcn_mfma_f32_16x16x32_bf16(a1, Bf[nt][ks], acc[1][nt], 0, 0, 0);
            }
        }
        float red[2][4];
#pragma unroll
        for (int ms = 0; ms < 2; ++ms)
#pragma unroll
            for (int r = 0; r < 4; ++r) {
                float s = 0.f;
#pragma unroll
                for (int nt = 0; nt < 2; ++nt)
                    s += fmaxf(acc[ms][nt][r] + b1v[nt], 0.f) * w2v[nt];
                red[ms][r] = s;
            }
#pragma unroll
        for (int mask = 1; mask <= 8; mask <<= 1)
#pragma unroll
            for (int ms = 0; ms < 2; ++ms)
#pragma unroll
                for (int r = 0; r < 4; ++r)
                    red[ms][r] += __shfl_xor(red[ms][r], mask);
        if (l15 == 0)
#pragma unroll
            for (int ms = 0; ms < 2; ++ms)
#pragma unroll
                for (int r = 0; r < 4; ++r)
                    part[w][ms * 16 + quad * 4 + r] = red[ms][r];
        __syncthreads();
        if (t < MT) {
            float s = b2v;
#pragma unroll
            for (int ww = 0; ww < 8; ++ww) s += part[ww][t];
            out[mb * MT + t] = s;
        }
    }
}

extern "C" void kernel_launch(void* const* d_in, const int* in_sizes, int n_in,
                              void* d_out, int out_size, void* d_ws, size_t ws_size,
                              hipStream_t stream) {
    const float* h     = (const float*)d_in[0];
    const int2*  edges = (const int2*)d_in[1];
    const float* W1    = (const float*)d_in[2];
    const float* b1    = (const float*)d_in[3];
    const float* W2    = (const float*)d_in[4];
    const float* b2    = (const float*)d_in[5];
    float* out = (float*)d_out;

    ushort* w1t = (ushort*)d_ws;                     // 128 KB
    ushort* hbf = (ushort*)((char*)d_ws + 131072);   // 51.2 MB

    prep_w1t<<<256, 256, 0, stream>>>(W1, w1t);
    if (ws_size >= 131072 + (size_t)25600000 * 2) {
        prep_hbf<<<12500, 256, 0, stream>>>(h, hbf);
        decoder<<<GRID_MAIN, BLK, 0, stream>>>(hbf, edges, w1t, b1, W2, b2, out);
    } else {
        decoder_f32<<<GRID_MAIN, BLK, 0, stream>>>(h, edges, w1t, b1, W2, b2, out);
    }
}

// Round 4
// 231.288 us; speedup vs baseline: 1.1340x; 1.1340x over previous
//
#include <hip/hip_runtime.h>
#include <hip/hip_bf16.h>

// MLPDecoder: scores[e] = relu((h[src]*h[dst]) @ W1 + b1) @ W2 + b2
// E=300000, D=256. bf16 MFMA, 1-barrier/iter pipeline.
// NOTE: prefetch regs are PLAIN NAMED VARS — r3's dynamic-indexed reg arrays
// spilled to scratch (WRITE_SIZE 1.2->34 MB) and regressed 82->118 us.

#define E_EDGES 300000
#define DIM 256
#define MT 32                    // edges per block-iteration
#define NTILES (E_EDGES / MT)    // 9375
#define BLK 512                  // 8 waves; each wave owns 32 N-cols
#define GRID_MAIN 512            // 2 blocks/CU
#define MAXJ 19                  // ceil(9375/512)

typedef short bf16x8 __attribute__((ext_vector_type(8)));
typedef float f32x4 __attribute__((ext_vector_type(4)));

__device__ __forceinline__ ushort f2bf(float f) {
    union { float f; unsigned u; } v; v.f = f;
    unsigned r = v.u + 0x7FFFu + ((v.u >> 16) & 1u);  // RNE
    return (ushort)(r >> 16);
}

// W1 fp32 [K=256][N=256] -> W1^T bf16 [N][K]
__global__ void prep_w1t(const float* __restrict__ w1, ushort* __restrict__ w1t) {
    int idx = blockIdx.x * 256 + threadIdx.x;
    int k = idx >> 8, n = idx & 255;
    w1t[n * 256 + k] = f2bf(w1[k * 256 + n]);
}

// h fp32 -> bf16
__global__ void prep_hbf(const float* __restrict__ h, ushort* __restrict__ hbf) {
    int i = blockIdx.x * 256 + threadIdx.x;
    const float4* src = (const float4*)h + (size_t)i * 2;
    float4 a = src[0], b = src[1];
    union { ushort s[8]; uint4 v; } o;
    o.s[0] = f2bf(a.x); o.s[1] = f2bf(a.y); o.s[2] = f2bf(a.z); o.s[3] = f2bf(a.w);
    o.s[4] = f2bf(b.x); o.s[5] = f2bf(b.y); o.s[6] = f2bf(b.z); o.s[7] = f2bf(b.w);
    ((uint4*)hbf)[i] = o.v;
}

__global__ __launch_bounds__(BLK, 4)
void decoder(const ushort* __restrict__ hbf, const int2* __restrict__ edges,
             const ushort* __restrict__ w1t, const float* __restrict__ b1,
             const float* __restrict__ w2, const float* __restrict__ b2p,
             float* __restrict__ out) {
    // stride 264: uniform bank spread for b128 ops; double-buffered
    __shared__ ushort xlds[2][MT][264];   // 33.8 KB
    __shared__ float part[2][8][MT];      // 2 KB
    __shared__ int2 eld[MAXJ * MT];       // this block's edge pairs (4.9 KB)

    const int t = threadIdx.x;
    const int w = t >> 6, lane = t & 63, quad = lane >> 4, l15 = lane & 15;
    const int bx = blockIdx.x, gdim = gridDim.x;
    const int J = (NTILES - bx + gdim - 1) / gdim;   // 18 or 19 tiles

    // ---- register-resident W1 frags: wave w owns N cols [32w, 32w+32) ----
    // B-frag (16x16x32): lane holds B[k = quad*8 + j][n = lane&15]
    bf16x8 Bf[2][8];   // 64 regs, loop indices all compile-time
#pragma unroll
    for (int nt = 0; nt < 2; ++nt) {
        int n = w * 32 + nt * 16 + l15;
#pragma unroll
        for (int ks = 0; ks < 8; ++ks)
            Bf[nt][ks] = *(const bf16x8*)(w1t + n * 256 + ks * 32 + quad * 8);
    }
    float b1v[2], w2v[2];
#pragma unroll
    for (int nt = 0; nt < 2; ++nt) {
        int n = w * 32 + nt * 16 + l15;
        b1v[nt] = b1[n];
        w2v[nt] = w2[n];
    }
    const float b2v = b2p[0];

    // ---- preload ALL this block's edge pairs into LDS ----
    for (int idx = t; idx < J * MT; idx += BLK)
        eld[idx] = edges[(size_t)(bx + (idx >> 5) * gdim) * MT + (idx & 31)];
    __syncthreads();

    const int sm = t >> 4;     // edge row in tile 0..31
    const int sc = t & 15;     // 32B chunk in row

    // single prefetch set; plain named regs (no spill risk). Depth>1 across a
    // barrier is useless anyway: __syncthreads drains vmcnt(0).
    uint4 sa, sb, da, db;

    auto issue = [&](int j) {
        int2 ed = eld[j * MT + sm];
        const uint4* ps = (const uint4*)(hbf + (size_t)ed.x * DIM) + sc * 2;
        const uint4* pd = (const uint4*)(hbf + (size_t)ed.y * DIM) + sc * 2;
        sa = ps[0]; sb = ps[1]; da = pd[0]; db = pd[1];
    };
    auto mul8 = [](uint4 a, uint4 b) -> uint4 {
        union U { uint4 v; __hip_bfloat162 h[4]; } ua, ub, o;
        ua.v = a; ub.v = b;
#pragma unroll
        for (int q = 0; q < 4; ++q) o.h[q] = __hmul2(ua.h[q], ub.h[q]);
        return o.v;
    };
    auto had = [&](int buf) {             // consume prefetch regs -> xlds[buf]
        uint4* dst = (uint4*)&xlds[buf][sm][sc * 16];
        dst[0] = mul8(sa, da);
        dst[1] = mul8(sb, db);
    };
    auto finalize = [&](int j, int par) { // write out tile j from part[par]
        if (t < MT) {
            float s = b2v;
#pragma unroll
            for (int ww = 0; ww < 8; ++ww) s += part[par][ww][t];
            out[(size_t)(bx + j * gdim) * MT + t] = s;
        }
    };

    // prologue
    issue(0);
    had(0);                   // xlds[0] <- tile 0 (visible after first sync)
    if (J > 1) issue(1);

    for (int j = 0; j < J; ++j) {
        const int par = j & 1;
        __syncthreads();
        if (j > 0) finalize(j - 1, par ^ 1);
        if (j + 1 < J) had(par ^ 1);      // consume regs (tile j+1)
        if (j + 2 < J) issue(j + 2);      // refill; flies across MFMA below

        // ---- MFMA on tile j from xlds[par] ----
        f32x4 acc[2][2];
#pragma unroll
        for (int ms = 0; ms < 2; ++ms)
#pragma unroll
            for (int nt = 0; nt < 2; ++nt)
                acc[ms][nt] = (f32x4){0.f, 0.f, 0.f, 0.f};
        const ushort* xb = &xlds[par][0][0];
#pragma unroll
        for (int ks = 0; ks < 8; ++ks) {
            int kb = ks * 32 + quad * 8;
            bf16x8 a0 = *(const bf16x8*)(xb + l15 * 264 + kb);
            bf16x8 a1 = *(const bf16x8*)(xb + (16 + l15) * 264 + kb);
#pragma unroll
            for (int nt = 0; nt < 2; ++nt) {
                acc[0][nt] = __builtin_amdgcn_mfma_f32_16x16x32_bf16(a0, Bf[nt][ks], acc[0][nt], 0, 0, 0);
                acc[1][nt] = __builtin_amdgcn_mfma_f32_16x16x32_bf16(a1, Bf[nt][ks], acc[1][nt], 0, 0, 0);
            }
        }
        // epilogue: relu(hid+b1).w2, butterfly over 16 n-lanes
        // C/D: row m = ms*16 + quad*4 + r, col n = w*32 + nt*16 + l15
        float red[2][4];
#pragma unroll
        for (int ms = 0; ms < 2; ++ms)
#pragma unroll
            for (int r = 0; r < 4; ++r) {
                float s = 0.f;
#pragma unroll
                for (int nt = 0; nt < 2; ++nt)
                    s += fmaxf(acc[ms][nt][r] + b1v[nt], 0.f) * w2v[nt];
                red[ms][r] = s;
            }
#pragma unroll
        for (int mask = 1; mask <= 8; mask <<= 1)
#pragma unroll
            for (int ms = 0; ms < 2; ++ms)
#pragma unroll
                for (int r = 0; r < 4; ++r)
                    red[ms][r] += __shfl_xor(red[ms][r], mask);
        if (l15 == 0)
#pragma unroll
            for (int ms = 0; ms < 2; ++ms)
#pragma unroll
                for (int r = 0; r < 4; ++r)
                    part[par][w][ms * 16 + quad * 4 + r] = red[ms][r];
    }

    __syncthreads();
    finalize(J - 1, (J - 1) & 1);
}

// fp32-gather fallback (only if ws too small for hbf; not expected to run)
__global__ __launch_bounds__(BLK, 4)
void decoder_f32(const float* __restrict__ h, const int2* __restrict__ edges,
                 const ushort* __restrict__ w1t, const float* __restrict__ b1,
                 const float* __restrict__ w2, const float* __restrict__ b2p,
                 float* __restrict__ out) {
    __shared__ ushort xlds[MT][264];
    __shared__ float part[8][MT];
    const int t = threadIdx.x;
    const int w = t >> 6, lane = t & 63, quad = lane >> 4, l15 = lane & 15;
    bf16x8 Bf[2][8];
#pragma unroll
    for (int nt = 0; nt < 2; ++nt)
#pragma unroll
        for (int ks = 0; ks < 8; ++ks)
            Bf[nt][ks] = *(const bf16x8*)(w1t + (w * 32 + nt * 16 + l15) * 256 + ks * 32 + quad * 8);
    float b1v[2], w2v[2];
#pragma unroll
    for (int nt = 0; nt < 2; ++nt) {
        b1v[nt] = b1[w * 32 + nt * 16 + l15];
        w2v[nt] = w2[w * 32 + nt * 16 + l15];
    }
    const float b2v = b2p[0];
    const int sm = t >> 4, sc = t & 15;
    for (int mb = blockIdx.x; mb < NTILES; mb += gridDim.x) {
        int2 ed = edges[mb * MT + sm];
        const float4* ps = (const float4*)(h + (size_t)ed.x * DIM) + sc * 4;
        const float4* pd = (const float4*)(h + (size_t)ed.y * DIM) + sc * 4;
        union { ushort s[16]; uint4 v[2]; } o;
#pragma unroll
        for (int jj = 0; jj < 4; ++jj) {
            float4 a = ps[jj], b = pd[jj];
            o.s[4 * jj + 0] = f2bf(a.x * b.x); o.s[4 * jj + 1] = f2bf(a.y * b.y);
            o.s[4 * jj + 2] = f2bf(a.z * b.z); o.s[4 * jj + 3] = f2bf(a.w * b.w);
        }
        uint4* dst = (uint4*)&xlds[sm][sc * 16];
        dst[0] = o.v[0]; dst[1] = o.v[1];
        __syncthreads();
        f32x4 acc[2][2];
#pragma unroll
        for (int ms = 0; ms < 2; ++ms)
#pragma unroll
            for (int nt = 0; nt < 2; ++nt) acc[ms][nt] = (f32x4){0.f,0.f,0.f,0.f};
#pragma unroll
        for (int ks = 0; ks < 8; ++ks) {
            int kb = ks * 32 + quad * 8;
            bf16x8 a0 = *(const bf16x8*)&xlds[l15][kb];
            bf16x8 a1 = *(const bf16x8*)&xlds[16 + l15][kb];
#pragma unroll
            for (int nt = 0; nt < 2; ++nt) {
                acc[0][nt] = __builtin_amdgcn_mfma_f32_16x16x32_bf16(a0, Bf[nt][ks], acc[0][nt], 0, 0, 0);
                acc[1][nt] = __builtin_amdgcn_mfma_f32_16x16x32_bf16(a1, Bf[nt][ks], acc[1][nt], 0, 0, 0);
            }
        }
        float red[2][4];
#pragma unroll
        for (int ms = 0; ms < 2; ++ms)
#pragma unroll
            for (int r = 0; r < 4; ++r) {
                float s = 0.f;
#pragma unroll
                for (int nt = 0; nt < 2; ++nt)
                    s += fmaxf(acc[ms][nt][r] + b1v[nt], 0.f) * w2v[nt];
                red[ms][r] = s;
            }
#pragma unroll
        for (int mask = 1; mask <= 8; mask <<= 1)
#pragma unroll
            for (int ms = 0; ms < 2; ++ms)
#pragma unroll
                for (int r = 0; r < 4; ++r)
                    red[ms][r] += __shfl_xor(red[ms][r], mask);
        if (l15 == 0)
#pragma unroll
            for (int ms = 0; ms < 2; ++ms)
#pragma unroll
                for (int r = 0; r < 4; ++r)
                    part[w][ms * 16 + quad * 4 + r] = red[ms][r];
        __syncthreads();
        if (t < MT) {
            float s = b2v;
#pragma unroll
            for (int ww = 0; ww < 8; ++ww) s += part[ww][t];
            out[mb * MT + t] = s;
        }
    }
}

extern "C" void kernel_launch(void* const* d_in, const int* in_sizes, int n_in,
                              void* d_out, int out_size, void* d_ws, size_t ws_size,
                              hipStream_t stream) {
    const float* h     = (const float*)d_in[0];
    const int2*  edges = (const int2*)d_in[1];
    const float* W1    = (const float*)d_in[2];
    const float* b1    = (const float*)d_in[3];
    const float* W2    = (const float*)d_in[4];
    const float* b2    = (const float*)d_in[5];
    float* out = (float*)d_out;

    ushort* w1t = (ushort*)d_ws;                     // 128 KB
    ushort* hbf = (ushort*)((char*)d_ws + 131072);   // 51.2 MB

    prep_w1t<<<256, 256, 0, stream>>>(W1, w1t);
    if (ws_size >= 131072 + (size_t)25600000 * 2) {
        prep_hbf<<<12500, 256, 0, stream>>>(h, hbf);
        decoder<<<GRID_MAIN, BLK, 0, stream>>>(hbf, edges, w1t, b1, W2, b2, out);
    } else {
        decoder_f32<<<GRID_MAIN, BLK, 0, stream>>>(h, edges, w1t, b1, W2, b2, out);
    }
}